// Round 6
// baseline (139.542 us; speedup 1.0000x reference)
//
#include <hip/hip_runtime.h>

#define NTOK 256
#define LOG2E 1.44269504088896340736f
#define LN_EPS 1e-5f

__device__ __forceinline__ float rdlane(float v, int lane) {
    return __int_as_float(__builtin_amdgcn_readlane(__float_as_int(v), lane));
}

// Grid: 512 blocks x 256 threads (4 waves). Wave w: row = blockIdx*2 + (w>>1),
// query half qsel = w&1. Lane l owns queries {qsel*64+l, qsel*64+l+128} and
// stages keys {l, l+64, l+128, l+192} in registers (4 x float4). The k-loop
// broadcasts each key via v_readlane -> SGPR; FMAs read the SGPR directly.
// Zero LDS, zero barriers, zero memory ops in the hot loop.
__global__ __launch_bounds__(256, 2)
void att_decoder_kernel(
    const float* __restrict__ x, const float* __restrict__ m,
    const float* __restrict__ sa_w_in, const float* __restrict__ sa_b_in,
    const float* __restrict__ sa_w_out, const float* __restrict__ sa_b_out,
    const float* __restrict__ ca_w_in, const float* __restrict__ ca_b_in,
    const float* __restrict__ ca_w_out, const float* __restrict__ ca_b_out,
    const float* __restrict__ ln1_g, const float* __restrict__ ln1_b,
    const float* __restrict__ ln2_g, const float* __restrict__ ln2_b,
    const float* __restrict__ ln3_g, const float* __restrict__ ln3_b,
    const float* __restrict__ f_w1, const float* __restrict__ f_b1,
    const float* __restrict__ f_ln_g, const float* __restrict__ f_ln_b,
    const float* __restrict__ f_w2, const float* __restrict__ f_b2,
    float* __restrict__ out)
{
    const int tid  = threadIdx.x;
    const int w    = tid >> 6;
    const int l    = tid & 63;
    const int row  = blockIdx.x * 2 + (w >> 1);
    const int qsel = w & 1;

    const float2* __restrict__ x2 = (const float2*)x;
    const float2* __restrict__ m2 = (const float2*)m;
    const int base = row * NTOK + l;

    // ---- stage this row's tokens: x (for SA keys + queries), m (for CA keys)
    float2 xr0 = x2[base];
    float2 xr1 = x2[base + 64];
    float2 xr2 = x2[base + 128];
    float2 xr3 = x2[base + 192];
    float2 mr0 = m2[base];
    float2 mr1 = m2[base + 64];
    float2 mr2 = m2[base + 128];
    float2 mr3 = m2[base + 192];

    // ---- LN1 on the 4 staged x tokens (closed form, d=2) ----
    const float g10 = ln1_g[0], b10 = ln1_b[0], g11 = ln1_g[1], b11 = ln1_b[1];
#define LN1(XV, O0, O1) { float d_ = 0.5f*(XV.x - XV.y);                    \
    float n_ = d_ * rsqrtf(d_*d_ + LN_EPS);                                  \
    O0 = n_*g10 + b10; O1 = -n_*g11 + b11; }
    float e0_0,e1_0,e0_1,e1_1,e0_2,e1_2,e0_3,e1_3;
    LN1(xr0, e0_0, e1_0); LN1(xr1, e0_1, e1_1);
    LN1(xr2, e0_2, e1_2); LN1(xr3, e0_3, e1_3);
#undef LN1

    // ---- SA KV (from LN1(x)) for the 4 staged keys: 16 named regs ----
    const float wk0 = sa_w_in[4],  wk1 = sa_w_in[5],  bk0 = sa_b_in[2];
    const float wk2 = sa_w_in[6],  wk3 = sa_w_in[7],  bk1 = sa_b_in[3];
    const float wv0 = sa_w_in[8],  wv1 = sa_w_in[9],  bv0 = sa_b_in[4];
    const float wv2 = sa_w_in[10], wv3 = sa_w_in[11], bv1 = sa_b_in[5];
#define PROJ(E0, E1, K0, K1, V0, V1)                                         \
    float K0 = E0*wk0 + E1*wk1 + bk0;  float K1 = E0*wk2 + E1*wk3 + bk1;     \
    float V0 = E0*wv0 + E1*wv1 + bv0;  float V1 = E0*wv2 + E1*wv3 + bv1;
    PROJ(e0_0, e1_0, sk0_0, sk1_0, sv0_0, sv1_0)
    PROJ(e0_1, e1_1, sk0_1, sk1_1, sv0_1, sv1_1)
    PROJ(e0_2, e1_2, sk0_2, sk1_2, sv0_2, sv1_2)
    PROJ(e0_3, e1_3, sk0_3, sk1_3, sv0_3, sv1_3)
#undef PROJ

    // ---- this lane's 2 queries (post-LN1 residual base) ----
    float h0a = qsel ? e0_1 : e0_0,  h1a = qsel ? e1_1 : e1_0;
    float h0b = qsel ? e0_3 : e0_2,  h1b = qsel ? e1_3 : e1_2;

    const float sc = 0.7071067811865476f * LOG2E;

    // ---- self-attention ----
    {
        float qe0a = (h0a*sa_w_in[0] + h1a*sa_w_in[1] + sa_b_in[0]) * sc;
        float qe1a = (h0a*sa_w_in[2] + h1a*sa_w_in[3] + sa_b_in[1]) * sc;
        float qe0b = (h0b*sa_w_in[0] + h1b*sa_w_in[1] + sa_b_in[0]) * sc;
        float qe1b = (h0b*sa_w_in[2] + h1b*sa_w_in[3] + sa_b_in[1]) * sc;
        float la = 0.f, a0a = 0.f, a1a = 0.f;
        float lb = 0.f, a0b = 0.f, a1b = 0.f;
#define STEP(K0, K1, V0, V1) {                                               \
        float k0_ = rdlane(K0, k), k1_ = rdlane(K1, k);                      \
        float v0_ = rdlane(V0, k), v1_ = rdlane(V1, k);                      \
        float pa = __builtin_amdgcn_exp2f(qe0a*k0_ + qe1a*k1_);              \
        float pb = __builtin_amdgcn_exp2f(qe0b*k0_ + qe1b*k1_);              \
        la += pa; a0a += pa*v0_; a1a += pa*v1_;                              \
        lb += pb; a0b += pb*v0_; a1b += pb*v1_; }
        #pragma unroll 2
        for (int k = 0; k < 64; ++k) {
            STEP(sk0_0, sk1_0, sv0_0, sv1_0)
            STEP(sk0_1, sk1_1, sv0_1, sv1_1)
            STEP(sk0_2, sk1_2, sv0_2, sv1_2)
            STEP(sk0_3, sk1_3, sv0_3, sv1_3)
        }
        float ra = 1.0f / la, rb = 1.0f / lb;
        a0a *= ra; a1a *= ra; a0b *= rb; a1b *= rb;
        h0a += a0a*sa_w_out[0] + a1a*sa_w_out[1] + sa_b_out[0];
        h1a += a0a*sa_w_out[2] + a1a*sa_w_out[3] + sa_b_out[1];
        h0b += a0b*sa_w_out[0] + a1b*sa_w_out[1] + sa_b_out[0];
        h1b += a0b*sa_w_out[2] + a1b*sa_w_out[3] + sa_b_out[1];
    }

    // ---- LN2 ----
    {
        float da = 0.5f*(h0a - h1a);
        float na = da * rsqrtf(da*da + LN_EPS);
        h0a =  na*ln2_g[0] + ln2_b[0];  h1a = -na*ln2_g[1] + ln2_b[1];
        float db = 0.5f*(h0b - h1b);
        float nb = db * rsqrtf(db*db + LN_EPS);
        h0b =  nb*ln2_g[0] + ln2_b[0];  h1b = -nb*ln2_g[1] + ln2_b[1];
    }

    // ---- CA KV (from m) — reuse register budget after SA KV dies ----
    const float cwk0 = ca_w_in[4],  cwk1 = ca_w_in[5],  cbk0 = ca_b_in[2];
    const float cwk2 = ca_w_in[6],  cwk3 = ca_w_in[7],  cbk1 = ca_b_in[3];
    const float cwv0 = ca_w_in[8],  cwv1 = ca_w_in[9],  cbv0 = ca_b_in[4];
    const float cwv2 = ca_w_in[10], cwv3 = ca_w_in[11], cbv1 = ca_b_in[5];
#define PROJ(MV, K0, K1, V0, V1)                                             \
    float K0 = MV.x*cwk0 + MV.y*cwk1 + cbk0;                                 \
    float K1 = MV.x*cwk2 + MV.y*cwk3 + cbk1;                                 \
    float V0 = MV.x*cwv0 + MV.y*cwv1 + cbv0;                                 \
    float V1 = MV.x*cwv2 + MV.y*cwv3 + cbv1;
    PROJ(mr0, ck0_0, ck1_0, cv0_0, cv1_0)
    PROJ(mr1, ck0_1, ck1_1, cv0_1, cv1_1)
    PROJ(mr2, ck0_2, ck1_2, cv0_2, cv1_2)
    PROJ(mr3, ck0_3, ck1_3, cv0_3, cv1_3)
#undef PROJ

    // ---- cross-attention ----
    {
        float qe0a = (h0a*ca_w_in[0] + h1a*ca_w_in[1] + ca_b_in[0]) * sc;
        float qe1a = (h0a*ca_w_in[2] + h1a*ca_w_in[3] + ca_b_in[1]) * sc;
        float qe0b = (h0b*ca_w_in[0] + h1b*ca_w_in[1] + ca_b_in[0]) * sc;
        float qe1b = (h0b*ca_w_in[2] + h1b*ca_w_in[3] + ca_b_in[1]) * sc;
        float la = 0.f, a0a = 0.f, a1a = 0.f;
        float lb = 0.f, a0b = 0.f, a1b = 0.f;
        #pragma unroll 2
        for (int k = 0; k < 64; ++k) {
            STEP(ck0_0, ck1_0, cv0_0, cv1_0)
            STEP(ck0_1, ck1_1, cv0_1, cv1_1)
            STEP(ck0_2, ck1_2, cv0_2, cv1_2)
            STEP(ck0_3, ck1_3, cv0_3, cv1_3)
        }
        float ra = 1.0f / la, rb = 1.0f / lb;
        a0a *= ra; a1a *= ra; a0b *= rb; a1b *= rb;
        h0a += a0a*ca_w_out[0] + a1a*ca_w_out[1] + ca_b_out[0];
        h1a += a0a*ca_w_out[2] + a1a*ca_w_out[3] + ca_b_out[1];
        h0b += a0b*ca_w_out[0] + a1b*ca_w_out[1] + ca_b_out[0];
        h1b += a0b*ca_w_out[2] + a1b*ca_w_out[3] + ca_b_out[1];
    }
#undef STEP

    // ---- LN3 ----
    {
        float da = 0.5f*(h0a - h1a);
        float na = da * rsqrtf(da*da + LN_EPS);
        h0a =  na*ln3_g[0] + ln3_b[0];  h1a = -na*ln3_g[1] + ln3_b[1];
        float db = 0.5f*(h0b - h1b);
        float nb = db * rsqrtf(db*db + LN_EPS);
        h0b =  nb*ln3_g[0] + ln3_b[0];  h1b = -nb*ln3_g[1] + ln3_b[1];
    }

    // ---- FFN: Linear(2,10) -> LN(10) -> ReLU -> Linear(10,2), residual ----
    #pragma unroll
    for (int tok = 0; tok < 2; ++tok) {
        float h0 = tok ? h0b : h0a;
        float h1 = tok ? h1b : h1a;
        float ff[10];
        #pragma unroll
        for (int i = 0; i < 10; ++i)
            ff[i] = h0*f_w1[2*i] + h1*f_w1[2*i+1] + f_b1[i];
        float mu = 0.f;
        #pragma unroll
        for (int i = 0; i < 10; ++i) mu += ff[i];
        mu *= 0.1f;
        float var = 0.f;
        #pragma unroll
        for (int i = 0; i < 10; ++i) { float d = ff[i] - mu; var += d * d; }
        var *= 0.1f;
        float r = rsqrtf(var + LN_EPS);
        float o0 = 0.f, o1 = 0.f;
        #pragma unroll
        for (int i = 0; i < 10; ++i) {
            float n = (ff[i] - mu) * r * f_ln_g[i] + f_ln_b[i];
            n = fmaxf(n, 0.f);
            o0 += n * f_w2[i];               // f_w2 is [2,10] row-major
            o1 += n * f_w2[10 + i];
        }
        if (tok) { h0b = h0 + o0 + f_b2[0]; h1b = h1 + o1 + f_b2[1]; }
        else     { h0a = h0 + o0 + f_b2[0]; h1a = h1 + o1 + f_b2[1]; }
    }

    float2* out2 = (float2*)out;
    const int qtok = qsel * 64 + l;
    out2[row * NTOK + qtok]       = make_float2(h0a, h1a);
    out2[row * NTOK + qtok + 128] = make_float2(h0b, h1b);
}

extern "C" void kernel_launch(void* const* d_in, const int* in_sizes, int n_in,
                              void* d_out, int out_size, void* d_ws, size_t ws_size,
                              hipStream_t stream) {
    const float* x        = (const float*)d_in[0];
    const float* m        = (const float*)d_in[1];
    const float* sa_w_in  = (const float*)d_in[2];
    const float* sa_b_in  = (const float*)d_in[3];
    const float* sa_w_out = (const float*)d_in[4];
    const float* sa_b_out = (const float*)d_in[5];
    const float* ca_w_in  = (const float*)d_in[6];
    const float* ca_b_in  = (const float*)d_in[7];
    const float* ca_w_out = (const float*)d_in[8];
    const float* ca_b_out = (const float*)d_in[9];
    const float* ln1_g    = (const float*)d_in[10];
    const float* ln1_b    = (const float*)d_in[11];
    const float* ln2_g    = (const float*)d_in[12];
    const float* ln2_b    = (const float*)d_in[13];
    const float* ln3_g    = (const float*)d_in[14];
    const float* ln3_b    = (const float*)d_in[15];
    const float* f_w1     = (const float*)d_in[16];
    const float* f_b1     = (const float*)d_in[17];
    const float* f_ln_g   = (const float*)d_in[18];
    const float* f_ln_b   = (const float*)d_in[19];
    const float* f_w2     = (const float*)d_in[20];
    const float* f_b2     = (const float*)d_in[21];

    const int nbatch = in_sizes[0] / (NTOK * 2);   // 1024
    att_decoder_kernel<<<nbatch / 2, 256, 0, stream>>>(
        x, m, sa_w_in, sa_b_in, sa_w_out, sa_b_out,
        ca_w_in, ca_b_in, ca_w_out, ca_b_out,
        ln1_g, ln1_b, ln2_g, ln2_b, ln3_g, ln3_b,
        f_w1, f_b1, f_ln_g, f_ln_b, f_w2, f_b2,
        (float*)d_out);
}

// Round 7
// 122.753 us; speedup vs baseline: 1.1368x; 1.1368x over previous
//
#include <hip/hip_runtime.h>

#define NTOK 256
#define LOG2E 1.44269504088896340736f
#define LN_EPS 1e-5f

typedef float v2f __attribute__((ext_vector_type(2)));

static __device__ __forceinline__ v2f splat(float s) { v2f r; r.x = s; r.y = s; return r; }

// Grid: 1024 blocks (1 per batch row) x 512 threads, 8 waves/SIMD at 4 blk/CU.
// Thread t: qp = t&127 -> owns queries {qp, qp+128} (packed as v2f lanes);
//           kh = t>>7  -> owns key quarter [kh*64, kh*64+64).
// KV delivered by uniform-address LDS broadcast (1 ds_read_b128 per key-step,
// serving 2 queries x 64 lanes = 128 pairs). All per-pair math is v2f ->
// v_pk_fma_f32. Split-k partials combined through LDS.
__global__ __launch_bounds__(512, 8)
void att_decoder_kernel(
    const float* __restrict__ x, const float* __restrict__ m,
    const float* __restrict__ sa_w_in, const float* __restrict__ sa_b_in,
    const float* __restrict__ sa_w_out, const float* __restrict__ sa_b_out,
    const float* __restrict__ ca_w_in, const float* __restrict__ ca_b_in,
    const float* __restrict__ ca_w_out, const float* __restrict__ ca_b_out,
    const float* __restrict__ ln1_g, const float* __restrict__ ln1_b,
    const float* __restrict__ ln2_g, const float* __restrict__ ln2_b,
    const float* __restrict__ ln3_g, const float* __restrict__ ln3_b,
    const float* __restrict__ f_w1, const float* __restrict__ f_b1,
    const float* __restrict__ f_ln_g, const float* __restrict__ f_ln_b,
    const float* __restrict__ f_w2, const float* __restrict__ f_b2,
    float* __restrict__ out)
{
    const int tid = threadIdx.x;
    const int row = blockIdx.x;
    const int qp  = tid & 127;
    const int kh  = tid >> 7;

    __shared__ float4 kv_sa[NTOK];        // 4 KB
    __shared__ float4 kv_ca[NTOK];        // 4 KB
    __shared__ v2f    part[3][512];       // 12 KB split-k partials

    const float2* __restrict__ x2 = (const float2*)x;
    const float2* __restrict__ m2 = (const float2*)m;

    // ---- stage KV: threads 0-255 -> SA (from LN1(x)), 256-511 -> CA (from m)
    {
        const int j = tid & 255;
        if (tid < 256) {
            float2 xv = x2[row * NTOK + j];
            float d = 0.5f * (xv.x - xv.y);
            float n = d * rsqrtf(d * d + LN_EPS);
            float h0 =  n * ln1_g[0] + ln1_b[0];
            float h1 = -n * ln1_g[1] + ln1_b[1];
            float4 kv;
            kv.x = h0*sa_w_in[4]  + h1*sa_w_in[5]  + sa_b_in[2];
            kv.y = h0*sa_w_in[6]  + h1*sa_w_in[7]  + sa_b_in[3];
            kv.z = h0*sa_w_in[8]  + h1*sa_w_in[9]  + sa_b_in[4];
            kv.w = h0*sa_w_in[10] + h1*sa_w_in[11] + sa_b_in[5];
            kv_sa[j] = kv;
        } else {
            float2 mv = m2[row * NTOK + j];
            float4 kv;
            kv.x = mv.x*ca_w_in[4]  + mv.y*ca_w_in[5]  + ca_b_in[2];
            kv.y = mv.x*ca_w_in[6]  + mv.y*ca_w_in[7]  + ca_b_in[3];
            kv.z = mv.x*ca_w_in[8]  + mv.y*ca_w_in[9]  + ca_b_in[4];
            kv.w = mv.x*ca_w_in[10] + mv.y*ca_w_in[11] + ca_b_in[5];
            kv_ca[j] = kv;
        }
    }

    // ---- own 2 queries (lanes of v2f), LN1 ----
    float2 xa = x2[row * NTOK + qp];
    float2 xb = x2[row * NTOK + qp + 128];
    v2f h0, h1;
    {
        float da = 0.5f * (xa.x - xa.y);
        float na = da * rsqrtf(da * da + LN_EPS);
        float db = 0.5f * (xb.x - xb.y);
        float nb = db * rsqrtf(db * db + LN_EPS);
        h0.x =  na*ln1_g[0] + ln1_b[0];  h0.y =  nb*ln1_g[0] + ln1_b[0];
        h1.x = -na*ln1_g[1] + ln1_b[1];  h1.y = -nb*ln1_g[1] + ln1_b[1];
    }

    __syncthreads();

    const float sc = 0.7071067811865476f * LOG2E;
    const int kbase = kh * 64;

    // ---- self-attention (packed v2f over 2 queries) ----
    {
        v2f qe0 = (h0*splat(sa_w_in[0]) + h1*splat(sa_w_in[1]) + splat(sa_b_in[0])) * splat(sc);
        v2f qe1 = (h0*splat(sa_w_in[2]) + h1*splat(sa_w_in[3]) + splat(sa_b_in[1])) * splat(sc);
        v2f l = splat(0.f), a0 = splat(0.f), a1 = splat(0.f);
        #pragma unroll 8
        for (int k = 0; k < 64; ++k) {
            float4 kv = kv_sa[kbase + k];          // uniform broadcast b128
            v2f s = qe0*splat(kv.x) + qe1*splat(kv.y);
            v2f p; p.x = __builtin_amdgcn_exp2f(s.x);
                   p.y = __builtin_amdgcn_exp2f(s.y);
            l += p; a0 += p*splat(kv.z); a1 += p*splat(kv.w);
        }
        part[0][tid] = l; part[1][tid] = a0; part[2][tid] = a1;
        __syncthreads();
        v2f L  = part[0][qp] + part[0][qp+128] + part[0][qp+256] + part[0][qp+384];
        v2f A0 = part[1][qp] + part[1][qp+128] + part[1][qp+256] + part[1][qp+384];
        v2f A1 = part[2][qp] + part[2][qp+128] + part[2][qp+256] + part[2][qp+384];
        v2f rl; rl.x = 1.0f / L.x; rl.y = 1.0f / L.y;
        A0 *= rl; A1 *= rl;
        h0 += A0*splat(sa_w_out[0]) + A1*splat(sa_w_out[1]) + splat(sa_b_out[0]);
        h1 += A0*splat(sa_w_out[2]) + A1*splat(sa_w_out[3]) + splat(sa_b_out[1]);
    }

    // ---- LN2 ----
    {
        float da = 0.5f * (h0.x - h1.x);
        float na = da * rsqrtf(da * da + LN_EPS);
        float db = 0.5f * (h0.y - h1.y);
        float nb = db * rsqrtf(db * db + LN_EPS);
        h0.x =  na*ln2_g[0] + ln2_b[0];  h0.y =  nb*ln2_g[0] + ln2_b[0];
        h1.x = -na*ln2_g[1] + ln2_b[1];  h1.y = -nb*ln2_g[1] + ln2_b[1];
    }

    __syncthreads();   // all SA-partial reads done before part[] reuse

    // ---- cross-attention ----
    {
        v2f qe0 = (h0*splat(ca_w_in[0]) + h1*splat(ca_w_in[1]) + splat(ca_b_in[0])) * splat(sc);
        v2f qe1 = (h0*splat(ca_w_in[2]) + h1*splat(ca_w_in[3]) + splat(ca_b_in[1])) * splat(sc);
        v2f l = splat(0.f), a0 = splat(0.f), a1 = splat(0.f);
        #pragma unroll 8
        for (int k = 0; k < 64; ++k) {
            float4 kv = kv_ca[kbase + k];
            v2f s = qe0*splat(kv.x) + qe1*splat(kv.y);
            v2f p; p.x = __builtin_amdgcn_exp2f(s.x);
                   p.y = __builtin_amdgcn_exp2f(s.y);
            l += p; a0 += p*splat(kv.z); a1 += p*splat(kv.w);
        }
        part[0][tid] = l; part[1][tid] = a0; part[2][tid] = a1;
        __syncthreads();
        if (tid >= 128) return;            // kh>0 lanes done
        v2f L  = part[0][qp] + part[0][qp+128] + part[0][qp+256] + part[0][qp+384];
        v2f A0 = part[1][qp] + part[1][qp+128] + part[1][qp+256] + part[1][qp+384];
        v2f A1 = part[2][qp] + part[2][qp+128] + part[2][qp+256] + part[2][qp+384];
        v2f rl; rl.x = 1.0f / L.x; rl.y = 1.0f / L.y;
        A0 *= rl; A1 *= rl;
        h0 += A0*splat(ca_w_out[0]) + A1*splat(ca_w_out[1]) + splat(ca_b_out[0]);
        h1 += A0*splat(ca_w_out[2]) + A1*splat(ca_w_out[3]) + splat(ca_b_out[1]);
    }

    // ---- LN3 ----
    {
        float da = 0.5f * (h0.x - h1.x);
        float na = da * rsqrtf(da * da + LN_EPS);
        float db = 0.5f * (h0.y - h1.y);
        float nb = db * rsqrtf(db * db + LN_EPS);
        h0.x =  na*ln3_g[0] + ln3_b[0];  h0.y =  nb*ln3_g[0] + ln3_b[0];
        h1.x = -na*ln3_g[1] + ln3_b[1];  h1.y = -nb*ln3_g[1] + ln3_b[1];
    }

    // ---- FFN (packed over 2 tokens): Lin(2,10)->LN(10)->ReLU->Lin(10,2)+res
    {
        v2f ff[10];
        #pragma unroll
        for (int i = 0; i < 10; ++i)
            ff[i] = h0*splat(f_w1[2*i]) + h1*splat(f_w1[2*i+1]) + splat(f_b1[i]);
        v2f mu = splat(0.f);
        #pragma unroll
        for (int i = 0; i < 10; ++i) mu += ff[i];
        mu *= splat(0.1f);
        v2f var = splat(0.f);
        #pragma unroll
        for (int i = 0; i < 10; ++i) { v2f d = ff[i] - mu; var += d * d; }
        var *= splat(0.1f);
        v2f r; r.x = rsqrtf(var.x + LN_EPS); r.y = rsqrtf(var.y + LN_EPS);
        v2f o0 = splat(0.f), o1 = splat(0.f);
        #pragma unroll
        for (int i = 0; i < 10; ++i) {
            v2f n = (ff[i] - mu) * r * splat(f_ln_g[i]) + splat(f_ln_b[i]);
            n.x = fmaxf(n.x, 0.f); n.y = fmaxf(n.y, 0.f);
            o0 += n * splat(f_w2[i]);        // f_w2 is [2,10] row-major
            o1 += n * splat(f_w2[10 + i]);
        }
        h0 += o0 + splat(f_b2[0]);
        h1 += o1 + splat(f_b2[1]);
    }

    float2* out2 = (float2*)out;
    out2[row * NTOK + qp]       = make_float2(h0.x, h1.x);
    out2[row * NTOK + qp + 128] = make_float2(h0.y, h1.y);
}

extern "C" void kernel_launch(void* const* d_in, const int* in_sizes, int n_in,
                              void* d_out, int out_size, void* d_ws, size_t ws_size,
                              hipStream_t stream) {
    const float* x        = (const float*)d_in[0];
    const float* m        = (const float*)d_in[1];
    const float* sa_w_in  = (const float*)d_in[2];
    const float* sa_b_in  = (const float*)d_in[3];
    const float* sa_w_out = (const float*)d_in[4];
    const float* sa_b_out = (const float*)d_in[5];
    const float* ca_w_in  = (const float*)d_in[6];
    const float* ca_b_in  = (const float*)d_in[7];
    const float* ca_w_out = (const float*)d_in[8];
    const float* ca_b_out = (const float*)d_in[9];
    const float* ln1_g    = (const float*)d_in[10];
    const float* ln1_b    = (const float*)d_in[11];
    const float* ln2_g    = (const float*)d_in[12];
    const float* ln2_b    = (const float*)d_in[13];
    const float* ln3_g    = (const float*)d_in[14];
    const float* ln3_b    = (const float*)d_in[15];
    const float* f_w1     = (const float*)d_in[16];
    const float* f_b1     = (const float*)d_in[17];
    const float* f_ln_g   = (const float*)d_in[18];
    const float* f_ln_b   = (const float*)d_in[19];
    const float* f_w2     = (const float*)d_in[20];
    const float* f_b2     = (const float*)d_in[21];

    const int nbatch = in_sizes[0] / (NTOK * 2);   // 1024
    att_decoder_kernel<<<nbatch, 512, 0, stream>>>(
        x, m, sa_w_in, sa_b_in, sa_w_out, sa_b_out,
        ca_w_in, ca_b_in, ca_w_out, ca_b_out,
        ln1_g, ln1_b, ln2_g, ln2_b, ln3_g, ln3_b,
        f_w1, f_b1, f_ln_g, f_ln_b, f_w2, f_b2,
        (float*)d_out);
}